// Round 1
// baseline (4710.624 us; speedup 1.0000x reference)
//
#include <hip/hip_runtime.h>
#include <hip/hip_cooperative_groups.h>

namespace cg = cooperative_groups;

#define BATCH 8
#define NPTS  2048
#define TPB   512
#define NWG   256
#define ITERS 50

#define KLOG2E    1442.6950408889634f    // log2(e)/eps
#define TWO_K     2885.3900817779268f    // 2*log2(e)/eps
#define INV_K     6.931471805599453e-4f  // eps*ln2 = 1/KLOG2E
#define INV_2K_SQ 1.2011325347955035e-7f // (1/(2K))^2
#define EPS_LN2   6.931471805599453e-4f  // eps*ln2
#define LN2       0.6931471805599453f
#define EPSV      1e-3f
#define NEGU      -1e30f
#define DEFER     30.0f
#define BIGD      1e10f

__device__ __forceinline__ float exp2fast(float x) { return __builtin_amdgcn_exp2f(x); }
__device__ __forceinline__ float log2fast(float x) { return __builtin_amdgcn_logf(x); }
__device__ __forceinline__ float clipf(float v)    { return fminf(fmaxf(v, -1.0f), 1.0f); }

// One half-iteration of log-domain Sinkhorn for 8 rows owned by this wave.
// rowpts: raw (unclipped) points of the row side, base of batch.
// colbuf: LDS float4 (2k*y0, 2k*y1, 2k*y2, u) for the column side.
// outv:   f or g array for this batch.
__device__ void half_update(const float* __restrict__ rowpts,
                            const float4* __restrict__ colbuf,
                            float* __restrict__ outv,
                            int nrows, int ncols, float eln,
                            int r0, int lane)
{
    if (r0 >= nrows) return;
    float x0[8], x1[8], x2[8], ar[8];
#pragma unroll
    for (int r = 0; r < 8; ++r) {
        const float* p = rowpts + (size_t)(r0 + r) * 3;
        float a = clipf(p[0]), bq = clipf(p[1]), cq = clipf(p[2]);
        x0[r] = a; x1[r] = bq; x2[r] = cq;
        ar[r] = -fmaf(a, a, fmaf(bq, bq, cq * cq)) * KLOG2E;   // -k*xx (row const, pulled out of LSE)
    }
    float Mv[8], Sv[8];
#pragma unroll
    for (int r = 0; r < 8; ++r) { Mv[r] = -3.0e38f; Sv[r] = 0.0f; }

    const int steps = (ncols + 63) >> 6;
    for (int s = 0; s < steps; ++s) {
        float4 yb = colbuf[(s << 6) + lane];
        float tt[8];
#pragma unroll
        for (int r = 0; r < 8; ++r)
            tt[r] = fmaf(x0[r], yb.x, fmaf(x1[r], yb.y, fmaf(x2[r], yb.z, yb.w)));
#pragma unroll
        for (int r = 0; r < 8; ++r) {
            float t = tt[r];
            if (__any(t > Mv[r] + DEFER)) {          // rare rescale (also first element)
                float Mn = fmaxf(Mv[r], t);
                Sv[r] = fmaf(Sv[r], exp2fast(Mv[r] - Mn), exp2fast(t - Mn));
                Mv[r] = Mn;
            } else if (__any(t > Mv[r] - DEFER)) {   // contributes; cold lanes underflow to 0
                Sv[r] += exp2fast(t - Mv[r]);
            } // else: whole wave below M-30 -> negligible, skip
        }
    }
    // merge per-lane (M,S) pairs across the wave, then finish f = eps*ln(m) - eps*LSE
    float fv[8];
#pragma unroll
    for (int r = 0; r < 8; ++r) {
        float Mr = Mv[r], Sr = Sv[r];
#pragma unroll
        for (int d = 1; d < 64; d <<= 1) {
            float Mo = __shfl_xor(Mr, d);
            float So = __shfl_xor(Sr, d);
            float Mn = fmaxf(Mr, Mo);
            Sr = fmaf(So, exp2fast(Mo - Mn), Sr * exp2fast(Mr - Mn));
            Mr = Mn;
        }
        fv[r] = fmaf(-EPS_LN2, ar[r] + Mr + log2fast(Sr), eln);
    }
    float v = fv[0];
#pragma unroll
    for (int r = 1; r < 8; ++r) v = (lane == r) ? fv[r] : v;
    if (lane < 8) outv[r0 + lane] = v;
}

__launch_bounds__(TPB, 1)
__global__ void pcl_kernel(const float* __restrict__ pred,
                           const float* __restrict__ gt,
                           const int* __restrict__ nlen,
                           const int* __restrict__ mlen,
                           float* __restrict__ fbuf,
                           float* __restrict__ gbuf,
                           float* __restrict__ parts,
                           float* __restrict__ out)
{
    __shared__ float4 xbuf[NPTS];   // (2k*x, v)  : 32 KB
    __shared__ float4 ybuf[NPTS];   // (2k*y, u)  : 32 KB
    cg::grid_group grid = cg::this_grid();

    const int tid  = threadIdx.x;
    const int wg   = blockIdx.x;
    const int b    = wg >> 5;        // batch (32 WGs per batch)
    const int wloc = wg & 31;
    const int wv   = tid >> 6;       // wave in WG (0..7)
    const int lane = tid & 63;
    const int n = nlen[b];
    const int m = mlen[b];
    const float nf = (float)n, mf = (float)m;
    const float* predb = pred + (size_t)b * NPTS * 3;
    const float* gtb   = gt   + (size_t)b * NPTS * 3;
    float* fb = fbuf + b * NPTS;
    float* gb = gbuf + b * NPTS;

    // init g = 0 (grid covers all batches)
    {
        int gidx = wg * TPB + tid;
        if (gidx < BATCH * NPTS) gbuf[gidx] = 0.0f;
    }
    // stage scaled clipped clouds into LDS
    for (int idx = tid; idx < NPTS; idx += TPB) {
        const float* p = predb + (size_t)idx * 3;
        xbuf[idx] = make_float4(clipf(p[0]) * TWO_K, clipf(p[1]) * TWO_K, clipf(p[2]) * TWO_K, 0.0f);
        const float* q = gtb + (size_t)idx * 3;
        ybuf[idx] = make_float4(clipf(q[0]) * TWO_K, clipf(q[1]) * TWO_K, clipf(q[2]) * TWO_K, 0.0f);
    }
    grid.sync();

    const float eln_m = EPSV * LN2 * log2fast(mf);   // eps*ln(m)
    const float eln_n = EPSV * LN2 * log2fast(nf);   // eps*ln(n)
    const int c  = wloc * 8 + wv;                    // chunk id 0..255 within batch
    const int r0 = c * 8;                            // first row/col of this wave's chunk

    for (int it = 0; it < ITERS; ++it) {
        // u-phase: ybuf.w = k*(g - yy)  (NEGU beyond m)
        for (int j = tid; j < NPTS; j += TPB) {
            float4 yb = ybuf[j];
            float yy = fmaf(yb.x, yb.x, fmaf(yb.y, yb.y, yb.z * yb.z)) * INV_2K_SQ;
            float u = NEGU;
            if (j < m) u = (gb[j] - yy) * KLOG2E;
            ybuf[j].w = u;
        }
        __syncthreads();
        half_update(predb, ybuf, fb, n, m, eln_m, r0, lane);   // f = update(g)
        grid.sync();
        // v-phase: xbuf.w = k*(f - xx)  (NEGU beyond n)
        for (int i = tid; i < NPTS; i += TPB) {
            float4 xb = xbuf[i];
            float xx = fmaf(xb.x, xb.x, fmaf(xb.y, xb.y, xb.z * xb.z)) * INV_2K_SQ;
            float vv = NEGU;
            if (i < n) vv = (fb[i] - xx) * KLOG2E;
            xbuf[i].w = vv;
        }
        __syncthreads();
        half_update(gtb, xbuf, gb, m, n, eln_n, r0, lane);     // g = update(f)
        grid.sync();
    }

    // refresh u with final g for the cost pass
    for (int j = tid; j < NPTS; j += TPB) {
        float4 yb = ybuf[j];
        float yy = fmaf(yb.x, yb.x, fmaf(yb.y, yb.y, yb.z * yb.z)) * INV_2K_SQ;
        float u = NEGU;
        if (j < m) u = (gb[j] - yy) * KLOG2E;
        ybuf[j].w = u;
    }
    __syncthreads();

    // ---- pass A: transport cost + chamfer x->y ----
    float wcost = 0.0f, chx = 0.0f;
    if (r0 < n) {
        float x0[8], x1[8], x2[8], xx[8], h[8], dmin[8];
#pragma unroll
        for (int r = 0; r < 8; ++r) {
            const float* p = predb + (size_t)(r0 + r) * 3;
            float a = clipf(p[0]), bq = clipf(p[1]), cq = clipf(p[2]);
            x0[r] = a; x1[r] = bq; x2[r] = cq;
            xx[r] = fmaf(a, a, fmaf(bq, bq, cq * cq));
            h[r]  = (r0 + r < n) ? (fb[r0 + r] - xx[r]) * KLOG2E : NEGU; // mask invalid rows
            dmin[r] = BIGD;
        }
        const int steps = (m + 63) >> 6;
        for (int s = 0; s < steps; ++s) {
            int jj = (s << 6) + lane;
            float4 yb = ybuf[jj];
            float yy = fmaf(yb.x, yb.x, fmaf(yb.y, yb.y, yb.z * yb.z)) * INV_2K_SQ;
            bool jvalid = jj < m;
#pragma unroll
            for (int r = 0; r < 8; ++r) {
                float dots = fmaf(x0[r], yb.x, fmaf(x1[r], yb.y, x2[r] * yb.z)); // 2k*(x.y)
                float e = h[r] + yb.w + dots;            // k*(f+g-C)
                float w = exp2fast(e);                   // n*m*P_ij
                float C = fmaxf(fmaf(dots, -INV_K, xx[r] + yy), 0.0f);
                wcost = fmaf(w, C, wcost);
                dmin[r] = fminf(dmin[r], jvalid ? C : BIGD);
            }
        }
#pragma unroll
        for (int r = 0; r < 8; ++r) {
            float d = dmin[r];
#pragma unroll
            for (int dd = 1; dd < 64; dd <<= 1) d = fminf(d, __shfl_xor(d, dd));
            if (r0 + r < n) chx += d;   // lane-uniform
        }
    }
#pragma unroll
    for (int dd = 1; dd < 64; dd <<= 1) wcost += __shfl_xor(wcost, dd);

    // ---- pass B: chamfer y->x ----
    float chy = 0.0f;
    if (r0 < m) {
        float y0[8], y1[8], y2[8], yyr[8], dmin[8];
#pragma unroll
        for (int r = 0; r < 8; ++r) {
            const float* q = gtb + (size_t)(r0 + r) * 3;
            float a = clipf(q[0]), bq = clipf(q[1]), cq = clipf(q[2]);
            y0[r] = a; y1[r] = bq; y2[r] = cq;
            yyr[r] = fmaf(a, a, fmaf(bq, bq, cq * cq));
            dmin[r] = BIGD;
        }
        const int steps = (n + 63) >> 6;
        for (int s = 0; s < steps; ++s) {
            int ii = (s << 6) + lane;
            float4 xb = xbuf[ii];
            float xx = fmaf(xb.x, xb.x, fmaf(xb.y, xb.y, xb.z * xb.z)) * INV_2K_SQ;
            bool ivalid = ii < n;
#pragma unroll
            for (int r = 0; r < 8; ++r) {
                float dots = fmaf(y0[r], xb.x, fmaf(y1[r], xb.y, y2[r] * xb.z)); // 2k*(x.y)
                float C = fmaxf(fmaf(dots, -INV_K, yyr[r] + xx), 0.0f);
                dmin[r] = fminf(dmin[r], ivalid ? C : BIGD);
            }
        }
#pragma unroll
        for (int r = 0; r < 8; ++r) {
            float d = dmin[r];
#pragma unroll
            for (int dd = 1; dd < 64; dd <<= 1) d = fminf(d, __shfl_xor(d, dd));
            if (r0 + r < m) chy += d;
        }
    }

    const int pslot = wg * 8 + wv;   // per-wave partials; batch b owns [256b, 256b+256)
    if (lane == 0) {
        parts[pslot]        = wcost;
        parts[2048 + pslot] = chx;
        parts[4096 + pslot] = chy;
    }
    grid.sync();

    // ---- final reduce (WG 0, one wave per batch) ----
    if (wg == 0) {
        int bb = wv;
        float cs = 0.0f, cxs = 0.0f, cys = 0.0f;
        for (int t2 = lane; t2 < 256; t2 += 64) {
            int slot = bb * 256 + t2;
            cs  += parts[slot];
            cxs += parts[2048 + slot];
            cys += parts[4096 + slot];
        }
#pragma unroll
        for (int dd = 1; dd < 64; dd <<= 1) {
            cs  += __shfl_xor(cs, dd);
            cxs += __shfl_xor(cxs, dd);
            cys += __shfl_xor(cys, dd);
        }
        if (lane == 0) {
            int nb = nlen[bb], mb = mlen[bb];
            float fnb = (float)nb, fmb = (float)mb;
            float cost = cs / (fnb * fmb);
            parts[6144 + bb] = sqrtf(fmaxf(cost, 0.0f)) + cxs / fnb + cys / fmb;
        }
        __syncthreads();
        if (tid == 0) {
            float acc = 0.0f;
            for (int i2 = 0; i2 < 8; ++i2) acc += parts[6144 + i2];
            out[0] = acc * 0.125f;   // mean over batch of (emd_b + cd_b)
        }
    }
}

extern "C" void kernel_launch(void* const* d_in, const int* in_sizes, int n_in,
                              void* d_out, int out_size, void* d_ws, size_t ws_size,
                              hipStream_t stream) {
    const float* pred = (const float*)d_in[0];
    const float* gt   = (const float*)d_in[1];
    const int*  nlen  = (const int*)d_in[2];
    const int*  mlen  = (const int*)d_in[3];
    float* ws    = (float*)d_ws;
    float* fbuf  = ws;                         // 16384
    float* gbuf  = ws + BATCH * NPTS;          // 16384
    float* parts = ws + 2 * BATCH * NPTS;      // 6152
    float* out   = (float*)d_out;

    void* kargs[] = { (void*)&pred, (void*)&gt, (void*)&nlen, (void*)&mlen,
                      (void*)&fbuf, (void*)&gbuf, (void*)&parts, (void*)&out };
    hipLaunchCooperativeKernel((void*)pcl_kernel, dim3(NWG), dim3(TPB), kargs, 0, stream);
}

// Round 2
// 3040.026 us; speedup vs baseline: 1.5495x; 1.5495x over previous
//
#include <hip/hip_runtime.h>
#include <hip/hip_cooperative_groups.h>

namespace cg = cooperative_groups;

#define BATCH 8
#define NPTS  2048
#define TPB   1024
#define NWG   256
#define ITERS 50
#define R     4

#define KLOG2E    1442.6950408889634f    // log2(e)/eps
#define TWO_K     2885.3900817779268f    // 2*log2(e)/eps
#define INV_K     6.931471805599453e-4f  // eps*ln2 = 1/KLOG2E
#define INV_2K_SQ 1.2011325347955035e-7f // (1/(2K))^2
#define EPS_LN2   6.931471805599453e-4f  // eps*ln2
#define LN2       0.6931471805599453f
#define EPSV      1e-3f
#define NEGU      -1e30f
#define BIGD      1e10f

__device__ __forceinline__ float exp2fast(float x) { return __builtin_amdgcn_exp2f(x); }
__device__ __forceinline__ float log2fast(float x) { return __builtin_amdgcn_logf(x); }
__device__ __forceinline__ float clipf(float v)    { return fminf(fmaxf(v, -1.0f), 1.0f); }

__device__ __forceinline__ float wsum(float v) {
#pragma unroll
    for (int d = 1; d < 64; d <<= 1) v += __shfl_xor(v, d);
    return v;
}
__device__ __forceinline__ float wmax(float v) {
#pragma unroll
    for (int d = 1; d < 64; d <<= 1) v = fmaxf(v, __shfl_xor(v, d));
    return v;
}
__device__ __forceinline__ float wmin(float v) {
#pragma unroll
    for (int d = 1; d < 64; d <<= 1) v = fminf(v, __shfl_xor(v, d));
    return v;
}

// One half-iteration of log-domain Sinkhorn for R rows owned by this wave.
// Branch-free fast path using persistent per-row log2-reference L[r] (= previous
// LSE2). Wave-uniform validity check; exact two-pass redo on failure (iter 0 / NaN /
// big drift). colbuf: LDS float4 (2k*y0, 2k*y1, 2k*y2, u=k*(g-yy) or NEGU).
__device__ __forceinline__ void half_fused(const float4* __restrict__ colbuf,
                                           const float* x0, const float* x1,
                                           const float* x2, const float* ar,
                                           float* __restrict__ outv, float* L,
                                           int nrows, int ncols, float eln,
                                           int r0, int lane)
{
    if (r0 >= nrows) return;
    const int steps = (ncols + 63) >> 6;

    float S[R];
#pragma unroll
    for (int r = 0; r < R; ++r) S[r] = 0.0f;

#pragma unroll 4
    for (int s = 0; s < steps; ++s) {
        float4 yb = colbuf[(s << 6) + lane];
#pragma unroll
        for (int r = 0; r < R; ++r) {
            float t = fmaf(x0[r], yb.x, fmaf(x1[r], yb.y, fmaf(x2[r], yb.z, yb.w)));
            S[r] += exp2fast(t - L[r]);
        }
    }

    float Ssum[R];
    bool redo = false;
#pragma unroll
    for (int r = 0; r < R; ++r) {
        Ssum[r] = wsum(S[r]);
        redo |= !(Ssum[r] >= 1e-19f && Ssum[r] <= 1e19f);   // catches 0/inf/NaN/drift
    }

    if (redo) {   // wave-uniform branch; exact two-pass recompute
        float Mn[R];
#pragma unroll
        for (int r = 0; r < R; ++r) Mn[r] = -3.0e38f;
        for (int s = 0; s < steps; ++s) {
            float4 yb = colbuf[(s << 6) + lane];
#pragma unroll
            for (int r = 0; r < R; ++r) {
                float t = fmaf(x0[r], yb.x, fmaf(x1[r], yb.y, fmaf(x2[r], yb.z, yb.w)));
                Mn[r] = fmaxf(Mn[r], t);
            }
        }
#pragma unroll
        for (int r = 0; r < R; ++r) { L[r] = wmax(Mn[r]); S[r] = 0.0f; }
        for (int s = 0; s < steps; ++s) {
            float4 yb = colbuf[(s << 6) + lane];
#pragma unroll
            for (int r = 0; r < R; ++r) {
                float t = fmaf(x0[r], yb.x, fmaf(x1[r], yb.y, fmaf(x2[r], yb.z, yb.w)));
                S[r] += exp2fast(t - L[r]);
            }
        }
#pragma unroll
        for (int r = 0; r < R; ++r) Ssum[r] = wsum(S[r]);
    }

    float fv[R];
#pragma unroll
    for (int r = 0; r < R; ++r) {
        L[r] += log2fast(Ssum[r]);                 // new LSE2 reference
        fv[r] = fmaf(-EPS_LN2, ar[r] + L[r], eln); // f = eps*ln(m) - eps*ln2*(ar+LSE2)
    }
    float v = fv[0];
#pragma unroll
    for (int r = 1; r < R; ++r) v = (lane == r) ? fv[r] : v;
    if (lane < R) outv[r0 + lane] = v;
}

__launch_bounds__(TPB, 1)
__global__ void pcl_kernel(const float* __restrict__ pred,
                           const float* __restrict__ gt,
                           const int* __restrict__ nlen,
                           const int* __restrict__ mlen,
                           float* __restrict__ fbuf,
                           float* __restrict__ gbuf,
                           float* __restrict__ parts,
                           float* __restrict__ out)
{
    __shared__ float4 xbuf[NPTS];   // (2k*x, v) : 32 KB
    __shared__ float4 ybuf[NPTS];   // (2k*y, u) : 32 KB
    cg::grid_group grid = cg::this_grid();

    const int tid  = threadIdx.x;
    const int wg   = blockIdx.x;
    const int b    = wg >> 5;        // batch (32 WGs per batch)
    const int wloc = wg & 31;
    const int wv   = tid >> 6;       // wave in WG (0..15)
    const int lane = tid & 63;
    const int n = nlen[b];
    const int m = mlen[b];
    const float nf = (float)n, mf = (float)m;
    const float* predb = pred + (size_t)b * NPTS * 3;
    const float* gtb   = gt   + (size_t)b * NPTS * 3;
    float* fb = fbuf + b * NPTS;
    float* gb = gbuf + b * NPTS;

    // init g = 0
    {
        int gidx = wg * TPB + tid;
        if (gidx < BATCH * NPTS) gbuf[gidx] = 0.0f;
    }
    // stage scaled clipped clouds into LDS
    for (int idx = tid; idx < NPTS; idx += TPB) {
        const float* p = predb + (size_t)idx * 3;
        xbuf[idx] = make_float4(clipf(p[0]) * TWO_K, clipf(p[1]) * TWO_K, clipf(p[2]) * TWO_K, 0.0f);
        const float* q = gtb + (size_t)idx * 3;
        ybuf[idx] = make_float4(clipf(q[0]) * TWO_K, clipf(q[1]) * TWO_K, clipf(q[2]) * TWO_K, 0.0f);
    }
    grid.sync();

    const float eln_m = EPSV * LN2 * log2fast(mf);   // eps*ln(m)
    const float eln_n = EPSV * LN2 * log2fast(nf);   // eps*ln(n)
    const int c  = wloc * 16 + wv;                   // chunk id 0..511 within batch
    const int r0 = c * R;                            // first row/col of this wave's chunk

    // hoist this wave's row data into registers (constant across all 50 iterations)
    float px0[R], px1[R], px2[R], pxx[R], pax[R];
#pragma unroll
    for (int r = 0; r < R; ++r) {
        const float* p = predb + (size_t)(r0 + r) * 3;
        float a = clipf(p[0]), bq = clipf(p[1]), cq = clipf(p[2]);
        px0[r] = a; px1[r] = bq; px2[r] = cq;
        pxx[r] = fmaf(a, a, fmaf(bq, bq, cq * cq));
        pax[r] = -pxx[r] * KLOG2E;
    }
    float qy0[R], qy1[R], qy2[R], qyy[R], qay[R];
#pragma unroll
    for (int r = 0; r < R; ++r) {
        const float* q = gtb + (size_t)(r0 + r) * 3;
        float a = clipf(q[0]), bq = clipf(q[1]), cq = clipf(q[2]);
        qy0[r] = a; qy1[r] = bq; qy2[r] = cq;
        qyy[r] = fmaf(a, a, fmaf(bq, bq, cq * cq));
        qay[r] = -qyy[r] * KLOG2E;
    }
    float Lf[R], Lg[R];
#pragma unroll
    for (int r = 0; r < R; ++r) { Lf[r] = 3.0e38f; Lg[r] = 3.0e38f; }  // forces exact redo at iter 0

    for (int it = 0; it < ITERS; ++it) {
        // u-phase: ybuf.w = k*(g - yy)  (NEGU beyond m)
        for (int j = tid; j < NPTS; j += TPB) {
            float4 yb = ybuf[j];
            float yy = fmaf(yb.x, yb.x, fmaf(yb.y, yb.y, yb.z * yb.z)) * INV_2K_SQ;
            ybuf[j].w = (j < m) ? (gb[j] - yy) * KLOG2E : NEGU;
        }
        __syncthreads();
        half_fused(ybuf, px0, px1, px2, pax, fb, Lf, n, m, eln_m, r0, lane);  // f = update(g)
        grid.sync();
        // v-phase: xbuf.w = k*(f - xx)  (NEGU beyond n)
        for (int i = tid; i < NPTS; i += TPB) {
            float4 xb = xbuf[i];
            float xx = fmaf(xb.x, xb.x, fmaf(xb.y, xb.y, xb.z * xb.z)) * INV_2K_SQ;
            xbuf[i].w = (i < n) ? (fb[i] - xx) * KLOG2E : NEGU;
        }
        __syncthreads();
        half_fused(xbuf, qy0, qy1, qy2, qay, gb, Lg, m, n, eln_n, r0, lane);  // g = update(f)
        grid.sync();
    }

    // refresh u with final g for the cost pass
    for (int j = tid; j < NPTS; j += TPB) {
        float4 yb = ybuf[j];
        float yy = fmaf(yb.x, yb.x, fmaf(yb.y, yb.y, yb.z * yb.z)) * INV_2K_SQ;
        ybuf[j].w = (j < m) ? (gb[j] - yy) * KLOG2E : NEGU;
    }
    __syncthreads();

    // ---- pass A: transport cost + chamfer x->y ----
    float wcost = 0.0f, chx = 0.0f;
    if (r0 < n) {
        float h[R], dmin[R];
#pragma unroll
        for (int r = 0; r < R; ++r) {
            h[r]  = (r0 + r < n) ? (fb[r0 + r] - pxx[r]) * KLOG2E : NEGU; // mask invalid rows
            dmin[r] = BIGD;
        }
        const int steps = (m + 63) >> 6;
        for (int s = 0; s < steps; ++s) {
            int jj = (s << 6) + lane;
            float4 yb = ybuf[jj];
            float yy = fmaf(yb.x, yb.x, fmaf(yb.y, yb.y, yb.z * yb.z)) * INV_2K_SQ;
            bool jvalid = jj < m;
#pragma unroll
            for (int r = 0; r < R; ++r) {
                float dots = fmaf(px0[r], yb.x, fmaf(px1[r], yb.y, px2[r] * yb.z)); // 2k*(x.y)
                float e = h[r] + yb.w + dots;            // k*(f+g-C)
                float w = exp2fast(e);                   // n*m*P_ij
                float C = fmaxf(fmaf(dots, -INV_K, pxx[r] + yy), 0.0f);
                wcost = fmaf(w, C, wcost);
                dmin[r] = fminf(dmin[r], jvalid ? C : BIGD);
            }
        }
#pragma unroll
        for (int r = 0; r < R; ++r) {
            float d = wmin(dmin[r]);
            if (r0 + r < n) chx += d;   // lane-uniform
        }
    }
    wcost = wsum(wcost);

    // ---- pass B: chamfer y->x ----
    float chy = 0.0f;
    if (r0 < m) {
        float dmin[R];
#pragma unroll
        for (int r = 0; r < R; ++r) dmin[r] = BIGD;
        const int steps = (n + 63) >> 6;
        for (int s = 0; s < steps; ++s) {
            int ii = (s << 6) + lane;
            float4 xb = xbuf[ii];
            float xx = fmaf(xb.x, xb.x, fmaf(xb.y, xb.y, xb.z * xb.z)) * INV_2K_SQ;
            bool ivalid = ii < n;
#pragma unroll
            for (int r = 0; r < R; ++r) {
                float dots = fmaf(qy0[r], xb.x, fmaf(qy1[r], xb.y, qy2[r] * xb.z));
                float C = fmaxf(fmaf(dots, -INV_K, qyy[r] + xx), 0.0f);
                dmin[r] = fminf(dmin[r], ivalid ? C : BIGD);
            }
        }
#pragma unroll
        for (int r = 0; r < R; ++r) {
            float d = wmin(dmin[r]);
            if (r0 + r < m) chy += d;
        }
    }

    const int pslot = wg * 16 + wv;   // per-wave partials; batch b owns [512b, 512b+512)
    if (lane == 0) {
        parts[pslot]         = wcost;
        parts[4096  + pslot] = chx;
        parts[8192  + pslot] = chy;
    }
    grid.sync();

    // ---- final reduce (WG 0, one wave per batch) ----
    if (wg == 0 && wv < 8) {
        int bb = wv;
        float cs = 0.0f, cxs = 0.0f, cys = 0.0f;
        for (int t2 = lane; t2 < 512; t2 += 64) {
            int slot = bb * 512 + t2;
            cs  += parts[slot];
            cxs += parts[4096 + slot];
            cys += parts[8192 + slot];
        }
        cs = wsum(cs); cxs = wsum(cxs); cys = wsum(cys);
        if (lane == 0) {
            int nb = nlen[bb], mb = mlen[bb];
            float fnb = (float)nb, fmb = (float)mb;
            float cost = cs / (fnb * fmb);
            parts[12288 + bb] = sqrtf(fmaxf(cost, 0.0f)) + cxs / fnb + cys / fmb;
        }
    }
    if (wg == 0) {
        __syncthreads();
        if (tid == 0) {
            float acc = 0.0f;
            for (int i2 = 0; i2 < 8; ++i2) acc += parts[12288 + i2];
            out[0] = acc * 0.125f;   // mean over batch of (emd_b + cd_b)
        }
    }
}

extern "C" void kernel_launch(void* const* d_in, const int* in_sizes, int n_in,
                              void* d_out, int out_size, void* d_ws, size_t ws_size,
                              hipStream_t stream) {
    const float* pred = (const float*)d_in[0];
    const float* gt   = (const float*)d_in[1];
    const int*  nlen  = (const int*)d_in[2];
    const int*  mlen  = (const int*)d_in[3];
    float* ws    = (float*)d_ws;
    float* fbuf  = ws;                         // 16384
    float* gbuf  = ws + BATCH * NPTS;          // 16384
    float* parts = ws + 2 * BATCH * NPTS;      // 12296
    float* out   = (float*)d_out;

    void* kargs[] = { (void*)&pred, (void*)&gt, (void*)&nlen, (void*)&mlen,
                      (void*)&fbuf, (void*)&gbuf, (void*)&parts, (void*)&out };
    hipLaunchCooperativeKernel((void*)pcl_kernel, dim3(NWG), dim3(TPB), kargs, 0, stream);
}